// Round 1
// 1830.053 us; speedup vs baseline: 1.5620x; 1.5620x over previous
//
#include <hip/hip_runtime.h>

#define TT 1000
#define FF 20
#define HH 256
#define OO 200
#define ZR 256           // zero-row index in padded int32 tables (257 rows x 256 cols)

typedef unsigned int uint;
typedef unsigned long long ull;

__device__ __forceinline__ int rfl(int v) { return __builtin_amdgcn_readfirstlane(v); }

// Dual-table signed toggle-gather batch: N rows from toggle mask m (wave-uniform),
// sign from current mask cur. Both tables share row indices -> one scalar stream,
// 2N 16B loads in flight. Empty slots hit zero row ZR. Exact int64 accumulation:
// (v ^ sm) - sm negates when sm = -1.
template<int N>
__device__ __forceinline__ void gstep2(const int* __restrict__ tabA, const int* __restrict__ tabB,
                                       uint& m, uint cur, int rowbase, int cx,
                                       long long* accA, long long* accB) {
    const int* pA[N];
    const int* pB[N];
    int sm[N];
#pragma unroll
    for (int u = 0; u < N; ++u) {
        int bb = __ffs((int)m);
        int k  = (bb ? bb : 1) - 1;
        int row = rfl(bb ? (rowbase + k) : ZR);
        int pos = rfl(bb ? (int)((cur >> k) & 1u) : 1);
        sm[u] = pos ? 0 : -1;
        size_t off = ((size_t)row << 8) + (size_t)cx;
        pA[u] = tabA + off;
        pB[u] = tabB + off;
        m &= (m - 1u);
    }
    int4 va[N], vb[N];
#pragma unroll
    for (int u = 0; u < N; ++u) { va[u] = *(const int4*)pA[u]; vb[u] = *(const int4*)pB[u]; }
#pragma unroll
    for (int u = 0; u < N; ++u) {
        accA[0] += (long long)((va[u].x ^ sm[u]) - sm[u]);
        accA[1] += (long long)((va[u].y ^ sm[u]) - sm[u]);
        accA[2] += (long long)((va[u].z ^ sm[u]) - sm[u]);
        accA[3] += (long long)((va[u].w ^ sm[u]) - sm[u]);
        accB[0] += (long long)((vb[u].x ^ sm[u]) - sm[u]);
        accB[1] += (long long)((vb[u].y ^ sm[u]) - sm[u]);
        accB[2] += (long long)((vb[u].z ^ sm[u]) - sm[u]);
        accB[3] += (long long)((vb[u].w ^ sm[u]) - sm[u]);
    }
}

// Adaptive-depth dual signed toggle gather; zero-row waste <= 3 per batch.
// Results committed to persistent LDS int64 drives via ds atomics (exact, order-free).
__device__ __forceinline__ void gather2(const int* __restrict__ tabA, const int* __restrict__ tabB,
                                        uint m, uint cur, int rowbase, int cx,
                                        long long* dstA, long long* dstB) {
    long long accA[4] = {0, 0, 0, 0}, accB[4] = {0, 0, 0, 0};
    while (m) {
        int pc = rfl(__popc(m));
        if (pc > 4)      gstep2<8>(tabA, tabB, m, cur, rowbase, cx, accA, accB);
        else if (pc > 2) gstep2<4>(tabA, tabB, m, cur, rowbase, cx, accA, accB);
        else             gstep2<2>(tabA, tabB, m, cur, rowbase, cx, accA, accB);
    }
#pragma unroll
    for (int c = 0; c < 4; ++c) {
        atomicAdd((ull*)&dstA[cx + c], (ull)accA[c]);
        atomicAdd((ull*)&dstB[cx + c], (ull)accB[c]);
    }
}

#define INV30 9.31322574615478515625e-10   // 2^-30, exact

// 2-barrier software pipeline. Iteration i:
//   Phase A: B(i) [waves 0-3] || D(i-1) [waves 4-7] || wx(i+1) [waves 8-11]
//            || x prefetch (i+2) || F(i-2) [wave 15]
//   Phase B: dual-gather t1(i): (W2Tq,V1q)->(pW2q,pV1q) [waves 0-7]
//            dual-gather t2(i-1): (WTq,V2q)->(pOq,pV2q) [waves 8-15]
// Dependencies: B(i) needs C(i-1) [prev phase B]; D(i-1) needs C(i-1), E(i-2);
// F(i-2) needs E(i-2); C(i) needs B(i)'s ballot; E(i-1) needs D(i-1)'s ballot.
__global__ __launch_bounds__(1024, 1) void snn_main(
    const float* __restrict__ x,
    const float* __restrict__ W1, const float* __restrict__ b1,
    const float* __restrict__ beta1,
    const float* __restrict__ b2, const float* __restrict__ beta2,
    const int* __restrict__ V1q, const int* __restrict__ V2q,
    const int* __restrict__ W2Tq, const int* __restrict__ WTq,
    const float* __restrict__ alpha_out, const float* __restrict__ beta_out,
    float* __restrict__ out)
{
    __shared__ float w1t_s[FF * HH];     // W1 transposed [f][h] (fp32, exact drive)
    __shared__ float wx_s[2][HH];        // b1 + W1 x_t, double-buffered by t parity
    __shared__ float xts[2][FF];         // x[t] double buffer
    __shared__ long long pV1q[HH];       // persistent int64 drives (scale 2^-30)
    __shared__ long long pV2q[HH];
    __shared__ long long pW2q[HH];
    __shared__ long long pOq[HH];
    __shared__ uint m1s[8], m2s[8];      // current 256-bit spike masks (8x32)
    __shared__ uint t1s[8], t2s[8];      // toggle masks this step

    const int tid = threadIdx.x;
    const int b   = blockIdx.x;
    const float* xg = x + (size_t)b * TT * FF;

    // ---- init ----
    for (int idx = tid; idx < FF * HH; idx += 1024) {
        int h = idx / FF, f = idx - h * FF;
        w1t_s[f * HH + h] = W1[idx];
    }
    if (tid < FF) { xts[0][tid] = xg[tid]; xts[1][tid] = xg[FF + tid]; }
    if (tid < 8) { m1s[tid] = 0u; m2s[tid] = 0u; t1s[tid] = 0u; t2s[tid] = 0u; }
    if (tid < HH) { pV1q[tid] = 0; pV2q[tid] = 0; pW2q[tid] = 0; pOq[tid] = 0; }

    // layer-1 state on tid 0..255
    float syn1 = 0.f, mem1 = 0.f, beta1r = 0.f;
    bool spk1 = false;
    if (tid < HH) beta1r = beta1[tid];

    // layer-2 state on tid 256..511
    float syn2 = 0.f, mem2 = 0.f, beta2r = 0.f, b2r = 0.f;
    bool spk2 = false;
    if (tid >= HH && tid < 2 * HH) { beta2r = beta2[tid - HH]; b2r = b2[tid - HH]; }

    // wx-compute bias on tid 512..767
    float b1r2 = 0.f;
    if (tid >= 512 && tid < 768) b1r2 = b1[tid - 512];

    // output state on tid 960..1023
    float synO[4] = {0,0,0,0}, memO[4] = {0,0,0,0}, accO[4] = {0,0,0,0};
    float aOr[4] = {0,0,0,0}, bOr[4] = {0,0,0,0};
    bool  spkO[4] = {false,false,false,false};
    if (tid >= 960) {
        int o0 = tid - 960;
#pragma unroll
        for (int r = 0; r < 4; ++r) {
            int o = o0 + (r << 6);
            if (o < OO) { aOr[r] = alpha_out[o]; bOr[r] = beta_out[o]; }
        }
    }
    __syncthreads();
    if (tid < HH) {   // wx for t=0
        float wx = b1[tid];
#pragma unroll
        for (int f = 0; f < FF; ++f) wx = fmaf(xts[0][f], w1t_s[f * HH + tid], wx);
        wx_s[0][tid] = wx;
    }
    __syncthreads();

    for (int i = 0; i < TT + 2; ++i) {
        // ================= Phase A =================
        if (tid < HH) {
            // B(i): layer-1 update, emit m1 + toggle t1
            if (i < TT) {
                float g1 = (float)((double)pV1q[tid] * INV30);
                syn1 = fmaf(0.95f, syn1, wx_s[i & 1][tid] + g1);
                mem1 = fmaf(beta1r, mem1, syn1) - (spk1 ? 1.f : 0.f);
                spk1 = mem1 > 1.0f;
                unsigned long long bal = __ballot(spk1 ? 1 : 0);
                if ((tid & 63) == 0) {
                    int w = tid >> 6;
                    uint n0 = (uint)bal, n1 = (uint)(bal >> 32);
                    t1s[2*w]   = m1s[2*w]   ^ n0;
                    t1s[2*w+1] = m1s[2*w+1] ^ n1;
                    m1s[2*w]   = n0;
                    m1s[2*w+1] = n1;
                }
            }
        } else if (tid < 2 * HH) {
            // D(i-1): layer-2 update, emit m2 + toggle t2
            if (i >= 1 && i <= TT) {
                int j = tid - HH;
                float gA = (float)((double)pW2q[j] * INV30);
                float gB = (float)((double)pV2q[j] * INV30);
                syn2 = fmaf(0.95f, syn2, b2r + gA + gB);
                mem2 = fmaf(beta2r, mem2, syn2) - (spk2 ? 1.f : 0.f);
                spk2 = mem2 > 1.0f;
                unsigned long long bal = __ballot(spk2 ? 1 : 0);
                if ((tid & 63) == 0) {
                    int w = j >> 6;
                    uint n0 = (uint)bal, n1 = (uint)(bal >> 32);
                    t2s[2*w]   = m2s[2*w]   ^ n0;
                    t2s[2*w+1] = m2s[2*w+1] ^ n1;
                    m2s[2*w]   = n0;
                    m2s[2*w+1] = n1;
                }
            }
        } else if (tid < 768) {
            // wx(i+1) into wx_s[(i+1)&1]
            if ((i + 1) < TT) {
                int j2 = tid - 512;
                const float* xx = xts[(i + 1) & 1];
                float wx = b1r2;
#pragma unroll
                for (int f = 0; f < FF; ++f) wx = fmaf(xx[f], w1t_s[f * HH + j2], wx);
                wx_s[(i + 1) & 1][j2] = wx;
            }
        } else if (tid < 768 + FF) {
            // prefetch x(i+2) into xts[i&1]
            if ((i + 2) < TT) xts[i & 1][tid - 768] = xg[(size_t)(i + 2) * FF + (tid - 768)];
        }
        // F(i-2): output layer (wave 15; disjoint from all branches above)
        if (tid >= 960 && i >= 2) {
            int tF = i - 2;
            int o0 = tid - 960;
            float mmax = -3.402823466e38f;
#pragma unroll
            for (int r = 0; r < 4; ++r) {
                int o = o0 + (r << 6);
                if (o < OO) {
                    float ot = (float)((double)pOq[o] * INV30);
                    synO[r] = fmaf(aOr[r], synO[r], ot);
                    memO[r] = fmaf(bOr[r], memO[r], synO[r]) - (spkO[r] ? 1.f : 0.f);
                    spkO[r] = memO[r] > 1.0f;
                    mmax = fmaxf(mmax, memO[r]);
                }
            }
#pragma unroll
            for (int off = 32; off; off >>= 1) mmax = fmaxf(mmax, __shfl_xor(mmax, off, 64));
            float ex[4]; float se = 0.f;
#pragma unroll
            for (int r = 0; r < 4; ++r) {
                int o = o0 + (r << 6);
                ex[r] = (o < OO) ? expf(memO[r] - mmax) : 0.f;
                se += ex[r];
            }
#pragma unroll
            for (int off = 32; off; off >>= 1) se += __shfl_xor(se, off, 64);
            if (tF > 10) {
#pragma unroll
                for (int r = 0; r < 4; ++r) accO[r] += ex[r] / se;
            }
        }
        __syncthreads();
        // ================= Phase B =================
        if (tid < 512) {
            // C(i): dual gather on t1(i) -> pW2q, pV1q
            if (i < TT) {
                int e = tid >> 6, cq = tid & 63;
                uint tm = (uint)rfl((int)t1s[e]);
                if (tm) {
                    uint cm = (uint)rfl((int)m1s[e]);
                    gather2(W2Tq, V1q, tm, cm, e << 5, cq << 2, pW2q, pV1q);
                }
            }
        } else {
            // E(i-1): dual gather on t2(i-1) -> pOq, pV2q
            if (i >= 1 && i <= TT) {
                int tt2 = tid - 512;
                int e = tt2 >> 6, cq = tt2 & 63;
                uint tm = (uint)rfl((int)t2s[e]);
                if (tm) {
                    uint cm = (uint)rfl((int)m2s[e]);
                    gather2(WTq, V2q, tm, cm, e << 5, cq << 2, pOq, pV2q);
                }
            }
        }
        __syncthreads();
    }

    if (tid >= 960) {
        int o0 = tid - 960;
#pragma unroll
        for (int r = 0; r < 4; ++r) {
            int o = o0 + (r << 6);
            if (o < OO) out[(size_t)b * OO + o] = accO[r];
        }
    }
}

// one-shot prep: padded 257x256 int32 fixed-point (2^30) tables, zero diagonal
// (V1q/V2q), zero row 256, WTq cols >= 200 zero.
__global__ void prep_kernel(const float* __restrict__ Vrec1, const float* __restrict__ Vrec2,
                            const float* __restrict__ W2, const float* __restrict__ Wout,
                            int* __restrict__ V1q, int* __restrict__ V2q,
                            int* __restrict__ W2Tq, int* __restrict__ WTq) {
    int idx = blockIdx.x * blockDim.x + threadIdx.x;   // 257*256 entries
    if (idx >= 257 * 256) return;
    int r = idx >> 8, c = idx & 255;
    float v1 = 0.f, v2 = 0.f, w2 = 0.f, wo = 0.f;
    if (r < 256) {
        if (r != c) { v1 = Vrec1[r * HH + c]; v2 = Vrec2[r * HH + c]; }
        w2 = W2[c * HH + r];
        if (c < OO) wo = Wout[c * HH + r];
    }
    const float S = 1073741824.0f;   // 2^30
    V1q[idx]  = __float2int_rn(v1 * S);
    V2q[idx]  = __float2int_rn(v2 * S);
    W2Tq[idx] = __float2int_rn(w2 * S);
    WTq[idx]  = __float2int_rn(wo * S);
}

extern "C" void kernel_launch(void* const* d_in, const int* in_sizes, int n_in,
                              void* d_out, int out_size, void* d_ws, size_t ws_size,
                              hipStream_t stream) {
    const float* x       = (const float*)d_in[0];
    const float* W1      = (const float*)d_in[1];
    const float* b1      = (const float*)d_in[2];
    const float* Vrec1   = (const float*)d_in[3];
    const float* beta1   = (const float*)d_in[4];
    const float* W2      = (const float*)d_in[5];
    const float* b2      = (const float*)d_in[6];
    const float* Vrec2   = (const float*)d_in[7];
    const float* beta2   = (const float*)d_in[8];
    const float* Wout    = (const float*)d_in[9];
    const float* alpha_o = (const float*)d_in[10];
    const float* beta_o  = (const float*)d_in[11];

    const int TBL = 257 * 256;       // int32 per padded table
    int* V1q  = (int*)d_ws;
    int* V2q  = V1q + TBL;
    int* W2Tq = V2q + TBL;
    int* WTq  = W2Tq + TBL;          // total ~1.05 MB of ws

    prep_kernel<<<(TBL + 255) / 256, 256, 0, stream>>>(Vrec1, Vrec2, W2, Wout,
                                                       V1q, V2q, W2Tq, WTq);
    snn_main<<<128, 1024, 0, stream>>>(x, W1, b1, beta1, b2, beta2,
                                       V1q, V2q, W2Tq, WTq,
                                       alpha_o, beta_o, (float*)d_out);
}